// Round 2
// baseline (71.273 us; speedup 1.0000x reference)
//
#include <hip/hip_runtime.h>

#define DELTA 0.05f
#define EPS 1e-8f

// ---------------------------------------------------------------------------
// Precompute per-gaussian packed record, padded to 64 B (one L1 line):
//   rec[0] = [S00,S01,S02,S11]  rec[1] = [S12,S22,mux,muy]  rec[2] = [muz,color,-,-]
//   rec[3] = unused pad
// Sigma = R diag(s^2) R^T  (scale_scale = 1)
// ---------------------------------------------------------------------------
__global__ __launch_bounds__(256) void precompute_gauss(
    const float* __restrict__ mu,
    const float* __restrict__ scaling,
    const float* __restrict__ rot,
    const float* __restrict__ color,
    float4* __restrict__ table, int G)
{
    int g = blockIdx.x * blockDim.x + threadIdx.x;
    if (g >= G) return;
    float qw = rot[g*4+0], qx = rot[g*4+1], qy = rot[g*4+2], qz = rot[g*4+3];
    float inv_norm = rsqrtf(qw*qw + qx*qx + qy*qy + qz*qz + EPS);
    qw *= inv_norm; qx *= inv_norm; qy *= inv_norm; qz *= inv_norm;
    float x2 = qx*qx, y2 = qy*qy, z2 = qz*qz;
    float xy = qx*qy, xz = qx*qz, yz = qy*qz;
    float wx = qw*qx, wy = qw*qy, wz = qw*qz;
    float R00 = 1.f - 2.f*(y2 + z2), R01 = 2.f*(xy - wz),       R02 = 2.f*(xz + wy);
    float R10 = 2.f*(xy + wz),       R11 = 1.f - 2.f*(x2 + z2), R12 = 2.f*(yz - wx);
    float R20 = 2.f*(xz - wy),       R21 = 2.f*(yz + wx),       R22 = 1.f - 2.f*(x2 + y2);
    float s0 = scaling[g*3+0], s1 = scaling[g*3+1], s2 = scaling[g*3+2];
    float d0 = s0*s0, d1 = s1*s1, d2 = s2*s2;
    float S00 = R00*R00*d0 + R01*R01*d1 + R02*R02*d2;
    float S01 = R00*R10*d0 + R01*R11*d1 + R02*R12*d2;
    float S02 = R00*R20*d0 + R01*R21*d1 + R02*R22*d2;
    float S11 = R10*R10*d0 + R11*R11*d1 + R12*R12*d2;
    float S12 = R10*R20*d0 + R11*R21*d1 + R12*R22*d2;
    float S22 = R20*R20*d0 + R21*R21*d1 + R22*R22*d2;
    float mx = mu[g*3+0], my = mu[g*3+1], mz = mu[g*3+2];
    float col = color[g];
    table[(size_t)g*4+0] = make_float4(S00, S01, S02, S11);
    table[(size_t)g*4+1] = make_float4(S12, S22, mx, my);
    table[(size_t)g*4+2] = make_float4(mz, col, 0.f, 0.f);
    // rec[3] left unwritten (pad only, never read)
}

// ---------------------------------------------------------------------------
// Main kernel: 8 lanes per point, 4 k-values per lane.
//   - idx load: one coalesced int4 per lane (wave reads 1 KB contiguous)
//   - 12 independent record gathers issued up front (MLP = 12/thread)
//   - reduction: in-thread over 4 tasks, then 3-step shuffle over 8 lanes
// ---------------------------------------------------------------------------
__global__ __launch_bounds__(256, 4) void gsvr_main4(
    const float* __restrict__ coords,
    const float* __restrict__ psf,
    const int*   __restrict__ idcs,
    const float4* __restrict__ table,
    float* __restrict__ out, int n_pts)
{
    int tid  = blockIdx.x * blockDim.x + threadIdx.x;
    int p    = tid >> 3;
    int lane = tid & 7;
    if (p >= n_pts) return;

    // coalesced: lanes 0..7 of point p read idcs[p*32 .. p*32+31]
    int4 gi = *reinterpret_cast<const int4*>(idcs + (size_t)p*32 + lane*4);
    int gs0 = gi.x, gs1 = gi.y, gs2 = gi.z, gs3 = gi.w;

    // issue all 12 gathers (independent; each record = exactly one 64-B line)
    const float4* rA = table + (size_t)gs0*4;
    const float4* rB = table + (size_t)gs1*4;
    const float4* rC = table + (size_t)gs2*4;
    const float4* rD = table + (size_t)gs3*4;
    float4 a0 = rA[0], a1 = rA[1], a2 = rA[2];
    float4 b0 = rB[0], b1 = rB[1], b2 = rB[2];
    float4 c0 = rC[0], c1 = rC[1], c2 = rC[2];
    float4 d0_ = rD[0], d1_ = rD[1], d2_ = rD[2];

    // per-point data (8-lane broadcast)
    float cx = coords[(size_t)p*3+0], cy = coords[(size_t)p*3+1], cz = coords[(size_t)p*3+2];
    const float* sp = psf + (size_t)p*9;
    float pa = sp[0], pb = sp[1], pc = sp[2], pe = sp[4], pf = sp[5], pi = sp[8];

    float wsum = 0.f, wcsum = 0.f;

    #pragma unroll
    for (int j = 0; j < 4; ++j) {
        float4 t0, t1, t2;
        if (j == 0) { t0 = a0; t1 = a1; t2 = a2; }
        else if (j == 1) { t0 = b0; t1 = b1; t2 = b2; }
        else if (j == 2) { t0 = c0; t1 = c1; t2 = c2; }
        else { t0 = d0_; t1 = d1_; t2 = d2_; }

        float a = t0.x + pa, b = t0.y + pb, c = t0.z + pc;
        float e = t0.w + pe, f = t1.x + pf, i = t1.y + pi;
        float vx = cx - t1.z, vy = cy - t1.w, vz = cz - t2.x;
        float col = t2.y;

        float ei_fh = e*i - f*f;
        float det = a*ei_fh - b*(b*i - f*c) + c*(b*f - e*c);
        float inv_det = 1.0f / (det + EPS);
        float i00 = ei_fh * inv_det;
        float i01 = (c*f - b*i) * inv_det;
        float i02 = (b*f - c*e) * inv_det;
        float i11 = (a*i - c*c) * inv_det;
        float i12 = (c*b - a*f) * inv_det;
        float i22 = (a*e - b*b) * inv_det;

        float q0 = i00*vx + i01*vy + i02*vz;
        float q1 = i01*vx + i11*vy + i12*vz;
        float q2 = i02*vx + i12*vy + i22*vz;
        float inner = vx*q0 + vy*q1 + vz*q2;

        float w = __expf(-0.5f * inner);
        wsum  += w;
        wcsum += w * col;
    }

    // reduce across the 8-lane group (XOR masks 1,2,4 stay within the group)
    #pragma unroll
    for (int m = 4; m >= 1; m >>= 1) {
        wsum  += __shfl_xor(wsum,  m);
        wcsum += __shfl_xor(wcsum, m);
    }
    if (lane == 0) out[p] = wcsum / (wsum + DELTA);
}

// ---------------------------------------------------------------------------
// Fallback (ws too small): lane-per-task, compute Sigma inline.
// ---------------------------------------------------------------------------
__global__ __launch_bounds__(256) void gsvr_fallback(
    const float* __restrict__ coords,
    const float* __restrict__ psf,
    const int*   __restrict__ idcs,
    const float* __restrict__ mu,
    const float* __restrict__ scaling,
    const float* __restrict__ rot,
    const float* __restrict__ color,
    float* __restrict__ out, int n_pts)
{
    int tid = blockIdx.x * blockDim.x + threadIdx.x;
    int p  = tid >> 5;
    int kk = tid & 31;
    if (p >= n_pts) return;

    float cx = coords[p*3+0], cy = coords[p*3+1], cz = coords[p*3+2];
    const float* sp = psf + (size_t)p*9;
    float pa = sp[0], pb = sp[1], pc = sp[2], pe = sp[4], pf = sp[5], pi = sp[8];

    int g = idcs[p*32 + kk];
    float qw = rot[g*4+0], qx = rot[g*4+1], qy = rot[g*4+2], qz = rot[g*4+3];
    float inv_norm = rsqrtf(qw*qw + qx*qx + qy*qy + qz*qz + EPS);
    qw *= inv_norm; qx *= inv_norm; qy *= inv_norm; qz *= inv_norm;
    float x2 = qx*qx, y2 = qy*qy, z2 = qz*qz;
    float xy = qx*qy, xz = qx*qz, yz = qy*qz;
    float wx = qw*qx, wy = qw*qy, wz = qw*qz;
    float R00 = 1.f - 2.f*(y2 + z2), R01 = 2.f*(xy - wz),       R02 = 2.f*(xz + wy);
    float R10 = 2.f*(xy + wz),       R11 = 1.f - 2.f*(x2 + z2), R12 = 2.f*(yz - wx);
    float R20 = 2.f*(xz - wy),       R21 = 2.f*(yz + wx),       R22 = 1.f - 2.f*(x2 + y2);
    float s0 = scaling[g*3+0], s1 = scaling[g*3+1], s2 = scaling[g*3+2];
    float dd0 = s0*s0, dd1 = s1*s1, dd2 = s2*s2;
    float S00 = R00*R00*dd0 + R01*R01*dd1 + R02*R02*dd2;
    float S01 = R00*R10*dd0 + R01*R11*dd1 + R02*R12*dd2;
    float S02 = R00*R20*dd0 + R01*R21*dd1 + R02*R22*dd2;
    float S11 = R10*R10*dd0 + R11*R11*dd1 + R12*R12*dd2;
    float S12 = R10*R20*dd0 + R11*R21*dd1 + R12*R22*dd2;
    float S22 = R20*R20*dd0 + R21*R21*dd1 + R22*R22*dd2;

    float a = S00 + pa, b = S01 + pb, c = S02 + pc;
    float e = S11 + pe, f = S12 + pf, i = S22 + pi;
    float vx = cx - mu[g*3+0], vy = cy - mu[g*3+1], vz = cz - mu[g*3+2];

    float ei_fh = e*i - f*f;
    float det = a*ei_fh - b*(b*i - f*c) + c*(b*f - e*c);
    float inv_det = 1.0f / (det + EPS);
    float i00 = ei_fh * inv_det;
    float i01 = (c*f - b*i) * inv_det;
    float i02 = (b*f - c*e) * inv_det;
    float i11 = (a*i - c*c) * inv_det;
    float i12 = (c*b - a*f) * inv_det;
    float i22 = (a*e - b*b) * inv_det;

    float q0 = i00*vx + i01*vy + i02*vz;
    float q1 = i01*vx + i11*vy + i12*vz;
    float q2 = i02*vx + i12*vy + i22*vz;
    float inner = vx*q0 + vy*q1 + vz*q2;

    float w  = __expf(-0.5f * inner);
    float wc = w * color[g];

    #pragma unroll
    for (int m = 16; m >= 1; m >>= 1) {
        w  += __shfl_xor(w,  m);
        wc += __shfl_xor(wc, m);
    }
    if (kk == 0) out[p] = wc / (w + DELTA);
}

extern "C" void kernel_launch(void* const* d_in, const int* in_sizes, int n_in,
                              void* d_out, int out_size, void* d_ws, size_t ws_size,
                              hipStream_t stream)
{
    const float* coords  = (const float*)d_in[0];
    const float* psf     = (const float*)d_in[1];
    const float* mu      = (const float*)d_in[2];
    const float* scaling = (const float*)d_in[3];
    const float* rot     = (const float*)d_in[4];
    const float* color   = (const float*)d_in[5];
    const int*   idcs    = (const int*)d_in[6];
    float* out = (float*)d_out;

    int n_pts = in_sizes[0] / 3;
    int G     = in_sizes[5];

    size_t need = (size_t)G * 16 * sizeof(float);   // 64 B per gaussian

    if (ws_size >= need) {
        float4* table = (float4*)d_ws;
        precompute_gauss<<<(G + 255) / 256, 256, 0, stream>>>(mu, scaling, rot, color, table, G);
        int threads = n_pts * 8;
        gsvr_main4<<<(threads + 255) / 256, 256, 0, stream>>>(
            coords, psf, idcs, table, out, n_pts);
    } else {
        int threads = n_pts * 32;
        gsvr_fallback<<<(threads + 255) / 256, 256, 0, stream>>>(
            coords, psf, idcs, mu, scaling, rot, color, out, n_pts);
    }
}

// Round 3
// 45.835 us; speedup vs baseline: 1.5550x; 1.5550x over previous
//
#include <hip/hip_runtime.h>
#include <hip/hip_fp16.h>

#define DELTA 0.05f
#define EPS 1e-8f

union H2F { __half2 h; float f; };

// ---------------------------------------------------------------------------
// Precompute per-gaussian packed 32-B record (two float4s):
//   r0 = [mux f32, muy f32, muz f32, (S00,S01) half2]
//   r1 = [(S02,S11) half2, (S12,S22) half2, (color,0) half2, pad]
// Sigma = R diag(s^2) R^T  (scale_scale = 1)
// ---------------------------------------------------------------------------
__global__ __launch_bounds__(256) void precompute_gauss(
    const float* __restrict__ mu,
    const float* __restrict__ scaling,
    const float* __restrict__ rot,
    const float* __restrict__ color,
    float4* __restrict__ table, int G)
{
    int g = blockIdx.x * blockDim.x + threadIdx.x;
    if (g >= G) return;
    float qw = rot[g*4+0], qx = rot[g*4+1], qy = rot[g*4+2], qz = rot[g*4+3];
    float inv_norm = rsqrtf(qw*qw + qx*qx + qy*qy + qz*qz + EPS);
    qw *= inv_norm; qx *= inv_norm; qy *= inv_norm; qz *= inv_norm;
    float x2 = qx*qx, y2 = qy*qy, z2 = qz*qz;
    float xy = qx*qy, xz = qx*qz, yz = qy*qz;
    float wx = qw*qx, wy = qw*qy, wz = qw*qz;
    float R00 = 1.f - 2.f*(y2 + z2), R01 = 2.f*(xy - wz),       R02 = 2.f*(xz + wy);
    float R10 = 2.f*(xy + wz),       R11 = 1.f - 2.f*(x2 + z2), R12 = 2.f*(yz - wx);
    float R20 = 2.f*(xz - wy),       R21 = 2.f*(yz + wx),       R22 = 1.f - 2.f*(x2 + y2);
    float s0 = scaling[g*3+0], s1 = scaling[g*3+1], s2 = scaling[g*3+2];
    float d0 = s0*s0, d1 = s1*s1, d2 = s2*s2;
    float S00 = R00*R00*d0 + R01*R01*d1 + R02*R02*d2;
    float S01 = R00*R10*d0 + R01*R11*d1 + R02*R12*d2;
    float S02 = R00*R20*d0 + R01*R21*d1 + R02*R22*d2;
    float S11 = R10*R10*d0 + R11*R11*d1 + R12*R12*d2;
    float S12 = R10*R20*d0 + R11*R21*d1 + R12*R22*d2;
    float S22 = R20*R20*d0 + R21*R21*d1 + R22*R22*d2;

    H2F u01, u21, u22, uc;
    u01.h = __floats2half2_rn(S00, S01);
    u21.h = __floats2half2_rn(S02, S11);
    u22.h = __floats2half2_rn(S12, S22);
    uc.h  = __floats2half2_rn(color[g], 0.f);

    float mx = mu[g*3+0], my = mu[g*3+1], mz = mu[g*3+2];
    table[(size_t)g*2+0] = make_float4(mx, my, mz, u01.f);
    table[(size_t)g*2+1] = make_float4(u21.f, u22.f, uc.f, 0.f);
}

// ---------------------------------------------------------------------------
// Main kernel: one lane per (point, k). 32 lanes per point, 2 points per wave.
// Streams (idcs, coords, psf, out) are non-temporal so the 3.2 MB table stays
// L2-resident.
// ---------------------------------------------------------------------------
__global__ __launch_bounds__(256) void gsvr_main(
    const float* __restrict__ coords,
    const float* __restrict__ psf,
    const int*   __restrict__ idcs,
    const float4* __restrict__ table,
    float* __restrict__ out, int n_pts)
{
    int tid = blockIdx.x * blockDim.x + threadIdx.x;
    int p  = tid >> 5;
    int kk = tid & 31;
    if (p >= n_pts) return;

    int g = __builtin_nontemporal_load(idcs + (size_t)p*32 + kk);

    // two aligned 16-B gathers; record = 32 B, never straddles a 64-B line
    float4 r0 = table[(size_t)g*2+0];
    float4 r1 = table[(size_t)g*2+1];

    float cx = __builtin_nontemporal_load(coords + (size_t)p*3+0);
    float cy = __builtin_nontemporal_load(coords + (size_t)p*3+1);
    float cz = __builtin_nontemporal_load(coords + (size_t)p*3+2);
    const float* sp = psf + (size_t)p*9;
    float pa = __builtin_nontemporal_load(sp+0);
    float pb = __builtin_nontemporal_load(sp+1);
    float pc = __builtin_nontemporal_load(sp+2);
    float pe = __builtin_nontemporal_load(sp+4);
    float pf = __builtin_nontemporal_load(sp+5);
    float pi = __builtin_nontemporal_load(sp+8);

    H2F u01, u21, u22, uc;
    u01.f = r0.w; u21.f = r1.x; u22.f = r1.y; uc.f = r1.z;
    float2 s01 = __half22float2(u01.h);
    float2 s21 = __half22float2(u21.h);
    float2 s22 = __half22float2(u22.h);
    float  col = __half22float2(uc.h).x;

    // sig = Sigma_g + Sigma_psf
    float a = s01.x + pa, b = s01.y + pb, c = s21.x + pc;
    float e = s21.y + pe, f = s22.x + pf, i = s22.y + pi;
    float vx = cx - r0.x, vy = cy - r0.y, vz = cz - r0.z;

    // explicit symmetric 3x3 inverse (same formula as reference)
    float ei_fh = e*i - f*f;
    float det = a*ei_fh - b*(b*i - f*c) + c*(b*f - e*c);
    float inv_det = 1.0f / (det + EPS);
    float i00 = ei_fh * inv_det;
    float i01 = (c*f - b*i) * inv_det;
    float i02 = (b*f - c*e) * inv_det;
    float i11 = (a*i - c*c) * inv_det;
    float i12 = (c*b - a*f) * inv_det;
    float i22 = (a*e - b*b) * inv_det;

    float q0 = i00*vx + i01*vy + i02*vz;
    float q1 = i01*vx + i11*vy + i12*vz;
    float q2 = i02*vx + i12*vy + i22*vz;
    float inner = vx*q0 + vy*q1 + vz*q2;

    float w  = __expf(-0.5f * inner);
    float wc = w * col;

    // butterfly reduce across the 32-lane group (masks <=16 stay in-half)
    #pragma unroll
    for (int m = 16; m >= 1; m >>= 1) {
        w  += __shfl_xor(w,  m);
        wc += __shfl_xor(wc, m);
    }
    if (kk == 0) __builtin_nontemporal_store(wc / (w + DELTA), out + p);
}

// ---------------------------------------------------------------------------
// Fallback (ws too small): lane-per-task, compute Sigma inline, all fp32.
// ---------------------------------------------------------------------------
__global__ __launch_bounds__(256) void gsvr_fallback(
    const float* __restrict__ coords,
    const float* __restrict__ psf,
    const int*   __restrict__ idcs,
    const float* __restrict__ mu,
    const float* __restrict__ scaling,
    const float* __restrict__ rot,
    const float* __restrict__ color,
    float* __restrict__ out, int n_pts)
{
    int tid = blockIdx.x * blockDim.x + threadIdx.x;
    int p  = tid >> 5;
    int kk = tid & 31;
    if (p >= n_pts) return;

    float cx = coords[p*3+0], cy = coords[p*3+1], cz = coords[p*3+2];
    const float* sp = psf + (size_t)p*9;
    float pa = sp[0], pb = sp[1], pc = sp[2], pe = sp[4], pf = sp[5], pi = sp[8];

    int g = idcs[p*32 + kk];
    float qw = rot[g*4+0], qx = rot[g*4+1], qy = rot[g*4+2], qz = rot[g*4+3];
    float inv_norm = rsqrtf(qw*qw + qx*qx + qy*qy + qz*qz + EPS);
    qw *= inv_norm; qx *= inv_norm; qy *= inv_norm; qz *= inv_norm;
    float x2 = qx*qx, y2 = qy*qy, z2 = qz*qz;
    float xy = qx*qy, xz = qx*qz, yz = qy*qz;
    float wx = qw*qx, wy = qw*qy, wz = qw*qz;
    float R00 = 1.f - 2.f*(y2 + z2), R01 = 2.f*(xy - wz),       R02 = 2.f*(xz + wy);
    float R10 = 2.f*(xy + wz),       R11 = 1.f - 2.f*(x2 + z2), R12 = 2.f*(yz - wx);
    float R20 = 2.f*(xz - wy),       R21 = 2.f*(yz + wx),       R22 = 1.f - 2.f*(x2 + y2);
    float s0 = scaling[g*3+0], s1 = scaling[g*3+1], s2 = scaling[g*3+2];
    float dd0 = s0*s0, dd1 = s1*s1, dd2 = s2*s2;
    float S00 = R00*R00*dd0 + R01*R01*dd1 + R02*R02*dd2;
    float S01 = R00*R10*dd0 + R01*R11*dd1 + R02*R12*dd2;
    float S02 = R00*R20*dd0 + R01*R21*dd1 + R02*R22*dd2;
    float S11 = R10*R10*dd0 + R11*R11*dd1 + R12*R12*dd2;
    float S12 = R10*R20*dd0 + R11*R21*dd1 + R12*R22*dd2;
    float S22 = R20*R20*dd0 + R21*R21*dd1 + R22*R22*dd2;

    float a = S00 + pa, b = S01 + pb, c = S02 + pc;
    float e = S11 + pe, f = S12 + pf, i = S22 + pi;
    float vx = cx - mu[g*3+0], vy = cy - mu[g*3+1], vz = cz - mu[g*3+2];

    float ei_fh = e*i - f*f;
    float det = a*ei_fh - b*(b*i - f*c) + c*(b*f - e*c);
    float inv_det = 1.0f / (det + EPS);
    float i00 = ei_fh * inv_det;
    float i01 = (c*f - b*i) * inv_det;
    float i02 = (b*f - c*e) * inv_det;
    float i11 = (a*i - c*c) * inv_det;
    float i12 = (c*b - a*f) * inv_det;
    float i22 = (a*e - b*b) * inv_det;

    float q0 = i00*vx + i01*vy + i02*vz;
    float q1 = i01*vx + i11*vy + i12*vz;
    float q2 = i02*vx + i12*vy + i22*vz;
    float inner = vx*q0 + vy*q1 + vz*q2;

    float w  = __expf(-0.5f * inner);
    float wc = w * color[g];

    #pragma unroll
    for (int m = 16; m >= 1; m >>= 1) {
        w  += __shfl_xor(w,  m);
        wc += __shfl_xor(wc, m);
    }
    if (kk == 0) out[p] = wc / (w + DELTA);
}

extern "C" void kernel_launch(void* const* d_in, const int* in_sizes, int n_in,
                              void* d_out, int out_size, void* d_ws, size_t ws_size,
                              hipStream_t stream)
{
    const float* coords  = (const float*)d_in[0];
    const float* psf     = (const float*)d_in[1];
    const float* mu      = (const float*)d_in[2];
    const float* scaling = (const float*)d_in[3];
    const float* rot     = (const float*)d_in[4];
    const float* color   = (const float*)d_in[5];
    const int*   idcs    = (const int*)d_in[6];
    float* out = (float*)d_out;

    int n_pts = in_sizes[0] / 3;
    int G     = in_sizes[5];

    size_t need = (size_t)G * 8 * sizeof(float);   // 32 B per gaussian

    if (ws_size >= need) {
        float4* table = (float4*)d_ws;
        precompute_gauss<<<(G + 255) / 256, 256, 0, stream>>>(mu, scaling, rot, color, table, G);
        int threads = n_pts * 32;
        gsvr_main<<<(threads + 255) / 256, 256, 0, stream>>>(
            coords, psf, idcs, table, out, n_pts);
    } else {
        int threads = n_pts * 32;
        gsvr_fallback<<<(threads + 255) / 256, 256, 0, stream>>>(
            coords, psf, idcs, mu, scaling, rot, color, out, n_pts);
    }
}

// Round 4
// 44.213 us; speedup vs baseline: 1.6120x; 1.0367x over previous
//
#include <hip/hip_runtime.h>
#include <hip/hip_fp16.h>

#define DELTA 0.05f
#define EPS 1e-8f

union H2F { __half2 h; float f; };
typedef int v2i __attribute__((ext_vector_type(2)));

// ---------------------------------------------------------------------------
// Precompute per-gaussian packed 32-B record (two float4s):
//   r0 = [mux f32, muy f32, muz f32, (S00,S01) half2]
//   r1 = [(S02,S11) half2, (S12,S22) half2, (color,0) half2, pad]
// Sigma = R diag(s^2) R^T  (scale_scale = 1)
// ---------------------------------------------------------------------------
__global__ __launch_bounds__(256) void precompute_gauss(
    const float* __restrict__ mu,
    const float* __restrict__ scaling,
    const float* __restrict__ rot,
    const float* __restrict__ color,
    float4* __restrict__ table, int G)
{
    int g = blockIdx.x * blockDim.x + threadIdx.x;
    if (g >= G) return;
    float qw = rot[g*4+0], qx = rot[g*4+1], qy = rot[g*4+2], qz = rot[g*4+3];
    float inv_norm = rsqrtf(qw*qw + qx*qx + qy*qy + qz*qz + EPS);
    qw *= inv_norm; qx *= inv_norm; qy *= inv_norm; qz *= inv_norm;
    float x2 = qx*qx, y2 = qy*qy, z2 = qz*qz;
    float xy = qx*qy, xz = qx*qz, yz = qy*qz;
    float wx = qw*qx, wy = qw*qy, wz = qw*qz;
    float R00 = 1.f - 2.f*(y2 + z2), R01 = 2.f*(xy - wz),       R02 = 2.f*(xz + wy);
    float R10 = 2.f*(xy + wz),       R11 = 1.f - 2.f*(x2 + z2), R12 = 2.f*(yz - wx);
    float R20 = 2.f*(xz - wy),       R21 = 2.f*(yz + wx),       R22 = 1.f - 2.f*(x2 + y2);
    float s0 = scaling[g*3+0], s1 = scaling[g*3+1], s2 = scaling[g*3+2];
    float d0 = s0*s0, d1 = s1*s1, d2 = s2*s2;
    float S00 = R00*R00*d0 + R01*R01*d1 + R02*R02*d2;
    float S01 = R00*R10*d0 + R01*R11*d1 + R02*R12*d2;
    float S02 = R00*R20*d0 + R01*R21*d1 + R02*R22*d2;
    float S11 = R10*R10*d0 + R11*R11*d1 + R12*R12*d2;
    float S12 = R10*R20*d0 + R11*R21*d1 + R12*R22*d2;
    float S22 = R20*R20*d0 + R21*R21*d1 + R22*R22*d2;

    H2F u01, u21, u22, uc;
    u01.h = __floats2half2_rn(S00, S01);
    u21.h = __floats2half2_rn(S02, S11);
    u22.h = __floats2half2_rn(S12, S22);
    uc.h  = __floats2half2_rn(color[g], 0.f);

    float mx = mu[g*3+0], my = mu[g*3+1], mz = mu[g*3+2];
    table[(size_t)g*2+0] = make_float4(mx, my, mz, u01.f);
    table[(size_t)g*2+1] = make_float4(u21.f, u22.f, uc.f, 0.f);
}

// ---------------------------------------------------------------------------
// Main kernel: 16 lanes per point, 2 k per lane.
//   - idx: one coalesced 8-B NT load per lane
//   - 4 independent 16-B record gathers in flight per thread (2x round 3)
//   - table unchanged: 32 B/record, 3.2 MB, L2-resident
//   - reduce: in-thread pair sum, then 4-step butterfly over 16 lanes
// ---------------------------------------------------------------------------
__global__ __launch_bounds__(256) void gsvr_main2(
    const float* __restrict__ coords,
    const float* __restrict__ psf,
    const int*   __restrict__ idcs,
    const float4* __restrict__ table,
    float* __restrict__ out, int n_pts)
{
    int tid  = blockIdx.x * blockDim.x + threadIdx.x;
    int p    = tid >> 4;
    int lane = tid & 15;
    if (p >= n_pts) return;

    // lanes 0..15 read idcs[p*32 .. p*32+31]: fully coalesced 128 B
    v2i gi = __builtin_nontemporal_load(
        reinterpret_cast<const v2i*>(idcs + (size_t)p*32 + lane*2));
    int g0 = gi[0], g1 = gi[1];

    // per-point broadcasts (independent of idx; issue while idx in flight)
    float cx = __builtin_nontemporal_load(coords + (size_t)p*3+0);
    float cy = __builtin_nontemporal_load(coords + (size_t)p*3+1);
    float cz = __builtin_nontemporal_load(coords + (size_t)p*3+2);
    const float* sp = psf + (size_t)p*9;
    float pa = __builtin_nontemporal_load(sp+0);
    float pb = __builtin_nontemporal_load(sp+1);
    float pc = __builtin_nontemporal_load(sp+2);
    float pe = __builtin_nontemporal_load(sp+4);
    float pf = __builtin_nontemporal_load(sp+5);
    float pi = __builtin_nontemporal_load(sp+8);

    // 4 independent gathers (each record = 32 B aligned, one line)
    const float4* ra = table + (size_t)g0*2;
    const float4* rb = table + (size_t)g1*2;
    float4 a0 = ra[0], a1 = ra[1];
    float4 b0 = rb[0], b1 = rb[1];

    float wsum = 0.f, wcsum = 0.f;

    #pragma unroll
    for (int j = 0; j < 2; ++j) {
        float4 r0 = (j == 0) ? a0 : b0;
        float4 r1 = (j == 0) ? a1 : b1;

        H2F u01, u21, u22, uc;
        u01.f = r0.w; u21.f = r1.x; u22.f = r1.y; uc.f = r1.z;
        float2 s01 = __half22float2(u01.h);
        float2 s21 = __half22float2(u21.h);
        float2 s22 = __half22float2(u22.h);
        float  col = __half22float2(uc.h).x;

        float a = s01.x + pa, b = s01.y + pb, c = s21.x + pc;
        float e = s21.y + pe, f = s22.x + pf, i = s22.y + pi;
        float vx = cx - r0.x, vy = cy - r0.y, vz = cz - r0.z;

        float ei_fh = e*i - f*f;
        float det = a*ei_fh - b*(b*i - f*c) + c*(b*f - e*c);
        float inv_det = 1.0f / (det + EPS);
        float i00 = ei_fh * inv_det;
        float i01 = (c*f - b*i) * inv_det;
        float i02 = (b*f - c*e) * inv_det;
        float i11 = (a*i - c*c) * inv_det;
        float i12 = (c*b - a*f) * inv_det;
        float i22 = (a*e - b*b) * inv_det;

        float q0 = i00*vx + i01*vy + i02*vz;
        float q1 = i01*vx + i11*vy + i12*vz;
        float q2 = i02*vx + i12*vy + i22*vz;
        float inner = vx*q0 + vy*q1 + vz*q2;

        float w = __expf(-0.5f * inner);
        wsum  += w;
        wcsum += w * col;
    }

    // butterfly reduce across the 16-lane group
    #pragma unroll
    for (int m = 8; m >= 1; m >>= 1) {
        wsum  += __shfl_xor(wsum,  m);
        wcsum += __shfl_xor(wcsum, m);
    }
    if (lane == 0) __builtin_nontemporal_store(wcsum / (wsum + DELTA), out + p);
}

// ---------------------------------------------------------------------------
// Fallback (ws too small): lane-per-task, compute Sigma inline, all fp32.
// ---------------------------------------------------------------------------
__global__ __launch_bounds__(256) void gsvr_fallback(
    const float* __restrict__ coords,
    const float* __restrict__ psf,
    const int*   __restrict__ idcs,
    const float* __restrict__ mu,
    const float* __restrict__ scaling,
    const float* __restrict__ rot,
    const float* __restrict__ color,
    float* __restrict__ out, int n_pts)
{
    int tid = blockIdx.x * blockDim.x + threadIdx.x;
    int p  = tid >> 5;
    int kk = tid & 31;
    if (p >= n_pts) return;

    float cx = coords[p*3+0], cy = coords[p*3+1], cz = coords[p*3+2];
    const float* sp = psf + (size_t)p*9;
    float pa = sp[0], pb = sp[1], pc = sp[2], pe = sp[4], pf = sp[5], pi = sp[8];

    int g = idcs[p*32 + kk];
    float qw = rot[g*4+0], qx = rot[g*4+1], qy = rot[g*4+2], qz = rot[g*4+3];
    float inv_norm = rsqrtf(qw*qw + qx*qx + qy*qy + qz*qz + EPS);
    qw *= inv_norm; qx *= inv_norm; qy *= inv_norm; qz *= inv_norm;
    float x2 = qx*qx, y2 = qy*qy, z2 = qz*qz;
    float xy = qx*qy, xz = qx*qz, yz = qy*qz;
    float wx = qw*qx, wy = qw*qy, wz = qw*qz;
    float R00 = 1.f - 2.f*(y2 + z2), R01 = 2.f*(xy - wz),       R02 = 2.f*(xz + wy);
    float R10 = 2.f*(xy + wz),       R11 = 1.f - 2.f*(x2 + z2), R12 = 2.f*(yz - wx);
    float R20 = 2.f*(xz - wy),       R21 = 2.f*(yz + wx),       R22 = 1.f - 2.f*(x2 + y2);
    float s0 = scaling[g*3+0], s1 = scaling[g*3+1], s2 = scaling[g*3+2];
    float dd0 = s0*s0, dd1 = s1*s1, dd2 = s2*s2;
    float S00 = R00*R00*dd0 + R01*R01*dd1 + R02*R02*dd2;
    float S01 = R00*R10*dd0 + R01*R11*dd1 + R02*R12*dd2;
    float S02 = R00*R20*dd0 + R01*R21*dd1 + R02*R22*dd2;
    float S11 = R10*R10*dd0 + R11*R11*dd1 + R12*R12*dd2;
    float S12 = R10*R20*dd0 + R11*R21*dd1 + R12*R22*dd2;
    float S22 = R20*R20*dd0 + R21*R21*dd1 + R22*R22*dd2;

    float a = S00 + pa, b = S01 + pb, c = S02 + pc;
    float e = S11 + pe, f = S12 + pf, i = S22 + pi;
    float vx = cx - mu[g*3+0], vy = cy - mu[g*3+1], vz = cz - mu[g*3+2];

    float ei_fh = e*i - f*f;
    float det = a*ei_fh - b*(b*i - f*c) + c*(b*f - e*c);
    float inv_det = 1.0f / (det + EPS);
    float i00 = ei_fh * inv_det;
    float i01 = (c*f - b*i) * inv_det;
    float i02 = (b*f - c*e) * inv_det;
    float i11 = (a*i - c*c) * inv_det;
    float i12 = (c*b - a*f) * inv_det;
    float i22 = (a*e - b*b) * inv_det;

    float q0 = i00*vx + i01*vy + i02*vz;
    float q1 = i01*vx + i11*vy + i12*vz;
    float q2 = i02*vx + i12*vy + i22*vz;
    float inner = vx*q0 + vy*q1 + vz*q2;

    float w  = __expf(-0.5f * inner);
    float wc = w * color[g];

    #pragma unroll
    for (int m = 16; m >= 1; m >>= 1) {
        w  += __shfl_xor(w,  m);
        wc += __shfl_xor(wc, m);
    }
    if (kk == 0) out[p] = wc / (w + DELTA);
}

extern "C" void kernel_launch(void* const* d_in, const int* in_sizes, int n_in,
                              void* d_out, int out_size, void* d_ws, size_t ws_size,
                              hipStream_t stream)
{
    const float* coords  = (const float*)d_in[0];
    const float* psf     = (const float*)d_in[1];
    const float* mu      = (const float*)d_in[2];
    const float* scaling = (const float*)d_in[3];
    const float* rot     = (const float*)d_in[4];
    const float* color   = (const float*)d_in[5];
    const int*   idcs    = (const int*)d_in[6];
    float* out = (float*)d_out;

    int n_pts = in_sizes[0] / 3;
    int G     = in_sizes[5];

    size_t need = (size_t)G * 8 * sizeof(float);   // 32 B per gaussian

    if (ws_size >= need) {
        float4* table = (float4*)d_ws;
        precompute_gauss<<<(G + 255) / 256, 256, 0, stream>>>(mu, scaling, rot, color, table, G);
        int threads = n_pts * 16;
        gsvr_main2<<<(threads + 255) / 256, 256, 0, stream>>>(
            coords, psf, idcs, table, out, n_pts);
    } else {
        int threads = n_pts * 32;
        gsvr_fallback<<<(threads + 255) / 256, 256, 0, stream>>>(
            coords, psf, idcs, mu, scaling, rot, color, out, n_pts);
    }
}